// Round 1
// baseline (282.565 us; speedup 1.0000x reference)
//
#include <hip/hip_runtime.h>
#include <math.h>

// Problem constants (reference: B=2, S=T=400, D=512)
#define BB 2
#define SS 400
#define DD 512
#define NROW (BB * SS)  // 800 rows (b,t) or (b,s)

// Workspace float layout:
//   wq2 [0,        409600)   : 2*(input@Wq + bq)      [B,S,D]
//   uh2 [409600,   819200)   : 2*(mb@Wc)              [B,S,D]
//   M   [819200,  1228800)   : mb@Wout_top            [B,S,D]
//   P   [1228800, 1638400)   : input@Wout_bot + bout  [B,S,D]
// total 1,638,400 floats = 6.55 MB

// ---------------------------------------------------------------------------
// K1: four row-GEMMs (800x512 @ 512x512), one per blockIdx.z.
// Thread owns one output column d for 8 rows; A reads are block-uniform ->
// scalar loads; W reads coalesced across lanes.
// ---------------------------------------------------------------------------
__global__ __launch_bounds__(256) void k1_gemm(
    const float* __restrict__ input, const float* __restrict__ mb,
    const float* __restrict__ Wq, const float* __restrict__ bq,
    const float* __restrict__ Wc, const float* __restrict__ Wout,
    const float* __restrict__ bout, float* __restrict__ ws)
{
    const int d  = blockIdx.x * 256 + threadIdx.x;  // 0..511
    const int r0 = blockIdx.y * 8;                  // row group of 8
    const int m  = blockIdx.z;                      // which matmul

    const float* __restrict__ A;
    const float* __restrict__ W;
    const float* __restrict__ bias;
    float* __restrict__ O;
    float scale;
    if (m == 0)      { A = input; W = Wq;            bias = bq;      O = ws;           scale = 2.f; }
    else if (m == 1) { A = mb;    W = Wc;            bias = nullptr; O = ws + 409600;  scale = 2.f; }
    else if (m == 2) { A = mb;    W = Wout;          bias = nullptr; O = ws + 819200;  scale = 1.f; }
    else             { A = input; W = Wout + DD*DD;  bias = bout;    O = ws + 1228800; scale = 1.f; }

    const float* __restrict__ Ar = A + r0 * DD;
    float acc[8];
    #pragma unroll
    for (int r = 0; r < 8; ++r) acc[r] = 0.f;

    #pragma unroll 4
    for (int e = 0; e < DD; ++e) {
        const float w = W[e * DD + d];
        #pragma unroll
        for (int r = 0; r < 8; ++r)
            acc[r] = fmaf(Ar[r * DD + e], w, acc[r]);
    }

    const float bv = bias ? bias[d] : 0.f;
    #pragma unroll
    for (int r = 0; r < 8; ++r)
        O[(r0 + r) * DD + d] = (acc[r] + bv) * scale;
}

// ---------------------------------------------------------------------------
// K2: one block per (b,t): scores v.tanh(wq+uh), mask, softmax, write align
// to out1 in [T,B,S] layout.  tanh(x) = 1 - 2/(exp(2x)+1); 2x prefolded.
// wq2/v reads are block-uniform (scalar path); uh2 reads are per-lane float4.
// ---------------------------------------------------------------------------
__global__ __launch_bounds__(256) void k2_attn(
    const float* __restrict__ ws, const float* __restrict__ v,
    const int* __restrict__ lens, float* __restrict__ align_out)
{
    const int bt  = blockIdx.x;            // b*SS + t
    const int b   = bt / SS;
    const int t   = bt - b * SS;
    const int tid = threadIdx.x;

    __shared__ float sc[SS];
    __shared__ float red[256];

    const float* __restrict__ wq2  = ws + bt * DD;           // 2*wq row (uniform)
    const float* __restrict__ uh2B = ws + 409600 + b * SS * DD;
    const int len = lens[b];

    for (int s = tid; s < SS; s += 256) {
        const float* __restrict__ u = uh2B + s * DD;
        float acc = 0.f;
        for (int e = 0; e < DD; e += 4) {
            const float4 u4 = *(const float4*)(u + e);
            const float x0 = wq2[e + 0] + u4.x;
            const float x1 = wq2[e + 1] + u4.y;
            const float x2 = wq2[e + 2] + u4.z;
            const float x3 = wq2[e + 3] + u4.w;
            const float r0 = __builtin_amdgcn_rcpf(__expf(x0) + 1.f);
            const float r1 = __builtin_amdgcn_rcpf(__expf(x1) + 1.f);
            const float r2 = __builtin_amdgcn_rcpf(__expf(x2) + 1.f);
            const float r3 = __builtin_amdgcn_rcpf(__expf(x3) + 1.f);
            acc = fmaf(v[e + 0], fmaf(-2.f, r0, 1.f), acc);
            acc = fmaf(v[e + 1], fmaf(-2.f, r1, 1.f), acc);
            acc = fmaf(v[e + 2], fmaf(-2.f, r2, 1.f), acc);
            acc = fmaf(v[e + 3], fmaf(-2.f, r3, 1.f), acc);
        }
        sc[s] = ((s < len) && (s != t)) ? acc : -INFINITY;
    }
    __syncthreads();

    // block max
    float lm = -INFINITY;
    for (int s = tid; s < SS; s += 256) lm = fmaxf(lm, sc[s]);
    red[tid] = lm;
    __syncthreads();
    #pragma unroll
    for (int o = 128; o > 0; o >>= 1) {
        if (tid < o) red[tid] = fmaxf(red[tid], red[tid + o]);
        __syncthreads();
    }
    const float mx = red[0];
    __syncthreads();

    // exp + block sum
    float ls = 0.f;
    for (int s = tid; s < SS; s += 256) {
        const float scs = sc[s];
        const float p = (scs == -INFINITY) ? 0.f : __expf(scs - mx);
        sc[s] = p;
        ls += p;
    }
    red[tid] = ls;
    __syncthreads();
    #pragma unroll
    for (int o = 128; o > 0; o >>= 1) {
        if (tid < o) red[tid] += red[tid + o];
        __syncthreads();
    }
    const float inv = 1.f / red[0];

    float* __restrict__ arow = align_out + ((size_t)(t * BB) + b) * SS;
    for (int s = tid; s < SS; s += 256) arow[s] = sc[s] * inv;
}

// ---------------------------------------------------------------------------
// K3: out0[t,b,d] = sum_s align[t,b,s] * M[b,s,d] + P[b,t,d]
// Thread owns column d for 8 rows; align reads are block-uniform (scalar).
// 800 rows / 8 = 100 groups; group never crosses a batch boundary (400%8==0).
// ---------------------------------------------------------------------------
__global__ __launch_bounds__(256) void k3_out(
    const float* __restrict__ ws, const float* __restrict__ align_out,
    float* __restrict__ out0)
{
    const int d  = blockIdx.x * 256 + threadIdx.x;
    const int r0 = blockIdx.y * 8;
    const int b  = r0 / SS;

    const float* __restrict__ Mb = ws + 819200 + b * SS * DD;
    const float* __restrict__ P  = ws + 1228800;

    float acc[8];
    #pragma unroll
    for (int j = 0; j < 8; ++j) acc[j] = 0.f;

    const int tbase = r0 - b * SS;  // t of row r0
    #pragma unroll 2
    for (int s = 0; s < SS; ++s) {
        const float mv = Mb[s * DD + d];
        #pragma unroll
        for (int j = 0; j < 8; ++j) {
            const int t = tbase + j;
            acc[j] = fmaf(align_out[((size_t)(t * BB) + b) * SS + s], mv, acc[j]);
        }
    }

    #pragma unroll
    for (int j = 0; j < 8; ++j) {
        const int row = r0 + j;
        const int t   = tbase + j;
        out0[((size_t)(t * BB) + b) * DD + d] = acc[j] + P[(size_t)row * DD + d];
    }
}

// ---------------------------------------------------------------------------
extern "C" void kernel_launch(void* const* d_in, const int* in_sizes, int n_in,
                              void* d_out, int out_size, void* d_ws, size_t ws_size,
                              hipStream_t stream)
{
    const float* input = (const float*)d_in[0];
    const float* mb    = (const float*)d_in[1];
    const int*   lens  = (const int*)d_in[2];
    const float* Wq    = (const float*)d_in[3];
    const float* bq    = (const float*)d_in[4];
    const float* Wc    = (const float*)d_in[5];
    const float* v     = (const float*)d_in[6];
    const float* Wout  = (const float*)d_in[7];
    const float* bout  = (const float*)d_in[8];

    float* out0 = (float*)d_out;              // [T,B,D] = 409600
    float* out1 = out0 + (size_t)BB * SS * DD; // [T,B,S] = 320000
    float* ws   = (float*)d_ws;

    hipLaunchKernelGGL(k1_gemm, dim3(2, 100, 4), dim3(256), 0, stream,
                       input, mb, Wq, bq, Wc, Wout, bout, ws);
    hipLaunchKernelGGL(k2_attn, dim3(NROW), dim3(256), 0, stream,
                       ws, v, lens, out1);
    hipLaunchKernelGGL(k3_out, dim3(2, 100), dim3(256), 0, stream,
                       ws, out1, out0);
}

// Round 2
// 207.117 us; speedup vs baseline: 1.3643x; 1.3643x over previous
//
#include <hip/hip_runtime.h>
#include <math.h>

// Problem constants (reference: B=2, S=T=400, D=512)
#define BB 2
#define SS 400
#define DD 512
#define TWO_LOG2E 2.8853900817779268f   // 2*log2(e): tanh(x) = 1 - 2/(exp2(TWO_LOG2E*x)+1)

#if __has_builtin(__builtin_amdgcn_exp2f)
#define EXP2F(x) __builtin_amdgcn_exp2f(x)
#else
#define EXP2F(x) exp2f(x)
#endif
#define RCPF(x) __builtin_amdgcn_rcpf(x)

// Workspace float layout:
//   wq2' [0,        409600) : TWO_LOG2E*(input@Wq + bq)   [B,S,D]
//   uh2' [409600,   819200) : TWO_LOG2E*(mb@Wc)           [B,S,D]
//   M    [819200,  1228800) : mb@Wout_top                 [B,S,D]
//   uh2T [1228800, 1638400) : uh2' transposed             [B,D,S]
//   vsum [1638400]          : sum(v)
// P = input@Wout_bot + bout is written by k1 (m==3) directly into out0.

// ---------------------------------------------------------------------------
// K1: four row-GEMMs (800x512 @ 512x512), one per blockIdx.z.
// Thread owns one output column d for 8 rows; A reads block-uniform (scalar),
// W reads coalesced across lanes.
// ---------------------------------------------------------------------------
__global__ __launch_bounds__(256) void k1_gemm(
    const float* __restrict__ input, const float* __restrict__ mb,
    const float* __restrict__ Wq, const float* __restrict__ bq,
    const float* __restrict__ Wc, const float* __restrict__ Wout,
    const float* __restrict__ bout, float* __restrict__ ws,
    float* __restrict__ out0)
{
    const int d  = blockIdx.x * 256 + threadIdx.x;  // 0..511
    const int r0 = blockIdx.y * 8;                  // row group of 8
    const int m  = blockIdx.z;                      // which matmul

    const float* __restrict__ A;
    const float* __restrict__ W;
    const float* __restrict__ bias;
    float scale;
    if (m == 0)      { A = input; W = Wq;            bias = bq;      scale = TWO_LOG2E; }
    else if (m == 1) { A = mb;    W = Wc;            bias = nullptr; scale = TWO_LOG2E; }
    else if (m == 2) { A = mb;    W = Wout;          bias = nullptr; scale = 1.f; }
    else             { A = input; W = Wout + DD*DD;  bias = bout;    scale = 1.f; }

    const float* __restrict__ Ar = A + r0 * DD;
    float acc[8];
    #pragma unroll
    for (int r = 0; r < 8; ++r) acc[r] = 0.f;

    #pragma unroll 4
    for (int e = 0; e < DD; ++e) {
        const float w = W[e * DD + d];
        #pragma unroll
        for (int r = 0; r < 8; ++r)
            acc[r] = fmaf(Ar[r * DD + e], w, acc[r]);
    }

    const float bv = bias ? bias[d] : 0.f;
    if (m == 3) {
        // write P directly into out0 in [T,B,D] layout (atomic base for k3)
        const int b = r0 / SS;          // uniform per block (400 % 8 == 0)
        const int tbase = r0 - b * SS;
        #pragma unroll
        for (int r = 0; r < 8; ++r)
            out0[((size_t)((tbase + r) * BB + b)) * DD + d] = acc[r] + bv;
    } else {
        float* __restrict__ O = (m == 0) ? ws : (m == 1) ? ws + 409600 : ws + 819200;
        #pragma unroll
        for (int r = 0; r < 8; ++r)
            O[(size_t)(r0 + r) * DD + d] = (acc[r] + bv) * scale;
    }
}

// ---------------------------------------------------------------------------
// K1T: transpose uh2' [B,S,D] -> uh2T [B,D,S] via 32x32 LDS tiles (+1 pad).
// Last block instead reduces v -> vsum.
// Grid: 2 b * 16 e-tiles * 13 s-tiles = 416 transpose blocks + 1 = 417.
// ---------------------------------------------------------------------------
__global__ __launch_bounds__(256) void k1t_transpose(
    const float* __restrict__ ws_uh,   // ws + 409600
    float* __restrict__ ws_T,          // ws + 1228800
    const float* __restrict__ v,
    float* __restrict__ vsum_slot)     // ws + 1638400
{
    const int idx = blockIdx.x;
    if (idx == 416) {
        const int tid = threadIdx.x;
        if (tid < 64) {
            float p = 0.f;
            for (int e = tid; e < DD; e += 64) p += v[e];
            #pragma unroll
            for (int off = 32; off > 0; off >>= 1) p += __shfl_xor(p, off);
            if (tid == 0) vsum_slot[0] = p;
        }
        return;
    }
    const int b   = idx / 208;
    const int rem = idx - b * 208;
    const int et  = rem / 13;
    const int st  = rem - et * 13;
    const int e0  = et * 32;
    const int s0  = st * 32;

    __shared__ float tile[32][33];
    const int col  = threadIdx.x & 31;
    const int row0 = threadIdx.x >> 5;  // 0..7

    #pragma unroll
    for (int k = 0; k < 4; ++k) {
        const int sl = row0 + 8 * k;
        const int s  = s0 + sl;
        if (s < SS) tile[sl][col] = ws_uh[(size_t)b * SS * DD + (size_t)s * DD + e0 + col];
    }
    __syncthreads();
    #pragma unroll
    for (int k = 0; k < 4; ++k) {
        const int el = row0 + 8 * k;
        const int s  = s0 + col;
        if (s < SS) ws_T[(size_t)b * DD * SS + (size_t)(e0 + el) * SS + s] = tile[col][el];
    }
}

// ---------------------------------------------------------------------------
// K2: one block per (b,t), 448 threads (7 waves), thread = s.
// score(s) = vsum - 2 * sum_e v[e] / (exp2(wq2'[e] + uh2T[e][s]) + 1)
// Coalesced dword loads of uh2T; wq2'/v uniform (scalar path). Then in-block
// softmax over the 448 lanes (400 valid) and coalesced align write.
// ---------------------------------------------------------------------------
__global__ __launch_bounds__(448) void k2_attn(
    const float* __restrict__ ws, const float* __restrict__ v,
    const int* __restrict__ lens, float* __restrict__ align_out)
{
    const int bt  = blockIdx.x;            // b*SS + t
    const int b   = bt / SS;
    const int t   = bt - b * SS;
    const int tid = threadIdx.x;           // = s

    const float* __restrict__ wq2 = ws + (size_t)bt * DD;            // uniform
    const float* __restrict__ uhT = ws + 1228800 + (size_t)b * DD * SS;
    const float  vsum = ws[1638400];                                  // uniform
    const int    len  = lens[b];

    const int  s     = tid;
    const int  sidx  = (s < SS) ? s : 0;
    const bool valid = (s < SS) && (s < len) && (s != t);
    const float* __restrict__ up = uhT + sidx;

    float acc0 = 0.f, acc1 = 0.f;
    for (int e = 0; e < DD; e += 8) {
        #pragma unroll
        for (int j = 0; j < 8; j += 2) {
            const float x0 = wq2[e + j]     + up[(size_t)(e + j)     * SS];
            const float x1 = wq2[e + j + 1] + up[(size_t)(e + j + 1) * SS];
            const float r0 = RCPF(EXP2F(x0) + 1.f);
            const float r1 = RCPF(EXP2F(x1) + 1.f);
            acc0 = fmaf(v[e + j],     r0, acc0);
            acc1 = fmaf(v[e + j + 1], r1, acc1);
        }
    }
    const float score = fmaf(-2.f, acc0 + acc1, vsum);
    const float sc = valid ? score : -INFINITY;

    __shared__ float wred[8];
    const int wid  = tid >> 6;
    const int lane = tid & 63;

    // block max
    float m = sc;
    #pragma unroll
    for (int off = 32; off > 0; off >>= 1) m = fmaxf(m, __shfl_xor(m, off));
    if (lane == 0) wred[wid] = m;
    __syncthreads();
    float mx = wred[0];
    #pragma unroll
    for (int w = 1; w < 7; ++w) mx = fmaxf(mx, wred[w]);
    __syncthreads();

    // exp + block sum
    const float p = valid ? __expf(sc - mx) : 0.f;
    float sm = p;
    #pragma unroll
    for (int off = 32; off > 0; off >>= 1) sm += __shfl_xor(sm, off);
    if (lane == 0) wred[wid] = sm;
    __syncthreads();
    float tot = wred[0];
    #pragma unroll
    for (int w = 1; w < 7; ++w) tot += wred[w];
    const float inv = RCPF(tot);

    if (s < SS) align_out[((size_t)(t * BB) + b) * SS + s] = p * inv;
}

// ---------------------------------------------------------------------------
// K3: out0[t,b,d] += sum_{s in chunk} align[t,b,s] * M[b,s,d]
// Grid (2 d-groups, 100 row-groups, 4 s-chunks) = 800 blocks; fp32 HW atomics.
// out0 pre-initialized with P by k1 (m==3).
// ---------------------------------------------------------------------------
__global__ __launch_bounds__(256) void k3_out(
    const float* __restrict__ ws, const float* __restrict__ align_out,
    float* __restrict__ out0)
{
    const int d  = blockIdx.x * 256 + threadIdx.x;
    const int r0 = blockIdx.y * 8;
    const int s0 = blockIdx.z * 100;
    const int b  = r0 / SS;
    const int tbase = r0 - b * SS;

    const float* __restrict__ Mb = ws + 819200 + (size_t)b * SS * DD;

    float acc[8];
    #pragma unroll
    for (int j = 0; j < 8; ++j) acc[j] = 0.f;

    #pragma unroll 2
    for (int s = s0; s < s0 + 100; ++s) {
        const float mv = Mb[(size_t)s * DD + d];
        #pragma unroll
        for (int j = 0; j < 8; ++j)
            acc[j] = fmaf(align_out[((size_t)((tbase + j) * BB) + b) * SS + s], mv, acc[j]);
    }

    #pragma unroll
    for (int j = 0; j < 8; ++j)
        unsafeAtomicAdd(&out0[((size_t)((tbase + j) * BB) + b) * DD + d], acc[j]);
}

// ---------------------------------------------------------------------------
extern "C" void kernel_launch(void* const* d_in, const int* in_sizes, int n_in,
                              void* d_out, int out_size, void* d_ws, size_t ws_size,
                              hipStream_t stream)
{
    const float* input = (const float*)d_in[0];
    const float* mb    = (const float*)d_in[1];
    const int*   lens  = (const int*)d_in[2];
    const float* Wq    = (const float*)d_in[3];
    const float* bq    = (const float*)d_in[4];
    const float* Wc    = (const float*)d_in[5];
    const float* v     = (const float*)d_in[6];
    const float* Wout  = (const float*)d_in[7];
    const float* bout  = (const float*)d_in[8];

    float* out0 = (float*)d_out;               // [T,B,D] = 409600
    float* out1 = out0 + (size_t)BB * SS * DD; // [T,B,S] = 320000
    float* ws   = (float*)d_ws;

    hipLaunchKernelGGL(k1_gemm, dim3(2, 100, 4), dim3(256), 0, stream,
                       input, mb, Wq, bq, Wc, Wout, bout, ws, out0);
    hipLaunchKernelGGL(k1t_transpose, dim3(417), dim3(256), 0, stream,
                       ws + 409600, ws + 1228800, v, ws + 1638400);
    hipLaunchKernelGGL(k2_attn, dim3(BB * SS), dim3(448), 0, stream,
                       ws, v, lens, out1);
    hipLaunchKernelGGL(k3_out, dim3(2, 100, 4), dim3(256), 0, stream,
                       ws, out1, out0);
}